// Round 11
// baseline (112184.949 us; speedup 1.0000x reference)
//
#include <hip/hip_runtime.h>
#include <math.h>

#define NB 32
#define TIN 512
#define TOUT 512
#define NENC 512
#define NATT 128
#define NU 1024
#define NG 4096
#define NPRE 256
#define NMEL 80

// ws offsets (floats)
#define WS_AH    0u
#define WS_AC    32768u
#define WS_DH    65536u
#define WS_DC    98304u
#define WS_ACTX  131072u
#define WS_AW    147456u
#define WS_AWCUM 163840u
#define WS_E     180224u
#define WS_PQ    196608u
#define WS_ZD    200704u                    // 20*32*4096
#define WS_ZA    2822144u                   // 14*32*4096
#define WS_PM    4657152u                   // 32*128*512 TRANSPOSED [b][a][t]
#define WS_PRE   6754304u                   // 513*32*256 (row 512 = zeros)
#define WS_STATE_ZERO_BYTES (200704u * 4u)
#define OUT_ALIGN ((size_t)NB * NMEL * TOUT + (size_t)NB * TOUT)

__device__ __forceinline__ float fsigm(float x) { return 1.f / (1.f + __expf(-x)); }
__device__ __forceinline__ float ftanh(float x) { return 1.f - 2.f / (__expf(2.f * x) + 1.f); }

// ---------------- setup kernels (verified) ----------------
__global__ __launch_bounds__(256) void prenet1_kernel(const float* __restrict__ dec,
                                                      const float* __restrict__ w1,
                                                      float* __restrict__ pre) {
    int t = blockIdx.x;
    __shared__ float xl[NB][NMEL];
    for (int i = threadIdx.x; i < NB * NMEL; i += 256) {
        int b = i / NMEL, m = i % NMEL;
        xl[b][m] = (t == 0) ? 0.0f : dec[(b * NMEL + m) * TOUT + (t - 1)];
    }
    __syncthreads();
    int j = threadIdx.x;
    float acc[NB];
#pragma unroll
    for (int b = 0; b < NB; b++) acc[b] = 0.0f;
    for (int m = 0; m < NMEL; m++) {
        float w = w1[j * NMEL + m];
#pragma unroll
        for (int b = 0; b < NB; b++) acc[b] += xl[b][m] * w;
    }
    for (int b = 0; b < NB; b++) pre[((size_t)t * NB + b) * NPRE + j] = fmaxf(acc[b], 0.0f);
}

__global__ __launch_bounds__(256) void prenet2_kernel(const float* __restrict__ w2,
                                                      float* __restrict__ pre) {
    int t = blockIdx.x;
    __shared__ float hl[NB][NPRE];
    for (int i = threadIdx.x; i < NB * NPRE; i += 256)
        hl[i / NPRE][i % NPRE] = pre[(size_t)t * NB * NPRE + i];
    __syncthreads();
    int j = threadIdx.x;
    float acc[NB];
#pragma unroll
    for (int b = 0; b < NB; b++) acc[b] = 0.0f;
    for (int k = 0; k < NPRE; k++) {
        float w = w2[j * NPRE + k];
#pragma unroll
        for (int b = 0; b < NB; b++) acc[b] += hl[b][k] * w;
    }
    for (int b = 0; b < NB; b++) pre[((size_t)t * NB + b) * NPRE + j] = fmaxf(acc[b], 0.0f);
}

// processed_memory TRANSPOSED: pmt[b][a][t]
__global__ __launch_bounds__(128) void pmt_kernel(const float* __restrict__ mem,
                                                  const float* __restrict__ mw,
                                                  float* __restrict__ pmt) {
    int b = blockIdx.y, t0 = blockIdx.x * 4;
    __shared__ float ml[4][NENC];
    for (int i = threadIdx.x; i < 4 * NENC; i += 128)
        ml[i / NENC][i % NENC] = mem[((size_t)b * TIN + t0 + i / NENC) * NENC + (i % NENC)];
    __syncthreads();
    int a = threadIdx.x;
    float acc[4] = {0, 0, 0, 0};
    for (int e = 0; e < NENC; e++) {
        float w = mw[a * NENC + e];
#pragma unroll
        for (int tt = 0; tt < 4; tt++) acc[tt] += ml[tt][e] * w;
    }
    *(float4*)&pmt[((size_t)b * NATT + a) * TIN + t0] = make_float4(acc[0], acc[1], acc[2], acc[3]);
}

// ---------------- z slice body (r9-verified, lane=column layout) ----------------
// slice s: 0-7 dwih@AH | 8-11 dwih@ACTX | 12-19 dwhh@DH |
//          20-21 awih@PRE(ts) | 22-25 awih@ACTX | 26-33 awhh@AH
__device__ __forceinline__ void z_slice_body(
        const float* __restrict__ dwih, const float* __restrict__ dwhh,
        const float* __restrict__ awih, const float* __restrict__ awhh,
        const float* __restrict__ ws_base, const float* __restrict__ pre_t,
        float* __restrict__ zd, float* __restrict__ za, int s, int col) {
    const float* ah   = ws_base + WS_AH;
    const float* dh   = ws_base + WS_DH;
    const float* actx = ws_base + WS_ACTX;
    const float* W; const float* x; int xs;
    if (s < 8)       { W = dwih + (size_t)col * 1536 + s * 128;              x = ah + s * 128;           xs = NU;   }
    else if (s < 12) { W = dwih + (size_t)col * 1536 + 1024 + (s - 8) * 128; x = actx + (s - 8) * 128;   xs = NENC; }
    else if (s < 20) { W = dwhh + (size_t)col * 1024 + (s - 12) * 128;       x = dh + (s - 12) * 128;    xs = NU;   }
    else if (s < 22) { W = awih + (size_t)col * 768 + (s - 20) * 128;        x = pre_t + (s - 20) * 128; xs = NPRE; }
    else if (s < 26) { W = awih + (size_t)col * 768 + 256 + (s - 22) * 128;  x = actx + (s - 22) * 128;  xs = NENC; }
    else             { W = awhh + (size_t)col * 1024 + (s - 26) * 128;       x = ah + (s - 26) * 128;    xs = NU;   }

    float acc[NB];
#pragma unroll
    for (int b = 0; b < NB; b++) acc[b] = 0.0f;
    for (int k4 = 0; k4 < 32; k4++) {
        float4 w4 = *(const float4*)(W + k4 * 4);
#pragma unroll
        for (int b = 0; b < NB; b++) {
            float4 x4 = *(const float4*)(x + (size_t)b * xs + k4 * 4);  // wave-uniform -> scalar
            acc[b] = fmaf(w4.x, x4.x, acc[b]);
            acc[b] = fmaf(w4.y, x4.y, acc[b]);
            acc[b] = fmaf(w4.z, x4.z, acc[b]);
            acc[b] = fmaf(w4.w, x4.w, acc[b]);
        }
    }
    float* zp = ((s < 20) ? (zd + (size_t)s * NB * NG) : (za + (size_t)(s - 20) * NB * NG)) + col;
#pragma unroll
    for (int b = 0; b < NB; b++) zp[(size_t)b * NG] = acc[b];
}

// ---------------- fused attention body (r5-r8 proven structure, 512 thr) ----------------
__device__ void attn_body(const float* __restrict__ memory, const int* __restrict__ mlen,
                          const float* __restrict__ wc, const float* __restrict__ ldw,
                          const float* __restrict__ vw,
                          float* __restrict__ ws, float* __restrict__ out_align,
                          int b, int step, int tid, float* sm) {
    float* awl = sm, *cuml = sm + 512, *pql = sm + 1024, *red = sm + 1152;
    awl[tid]  = ws[WS_AW + b * 512 + tid];
    cuml[tid] = ws[WS_AWCUM + b * 512 + tid];
    if (tid < NATT) pql[tid] = ws[WS_PQ + b * NATT + tid];
    __syncthreads();
    int t = tid;
    float loc[32];
#pragma unroll
    for (int f = 0; f < 32; ++f) loc[f] = 0.f;
    for (int d = 0; d < 31; ++d) {
        int tp = t + d - 15;
        int tc = min(max(tp, 0), 511);
        bool ok = (tp >= 0) && (tp < 512);
        float a_ = ok ? awl[tc] : 0.f;
        float c_ = ok ? cuml[tc] : 0.f;
#pragma unroll
        for (int f = 0; f < 32; ++f)
            loc[f] = fmaf(a_, wc[f * 62 + d], fmaf(c_, wc[f * 62 + 31 + d], loc[f]));
    }
    float e = 0.f;
    const float* pmt = ws + WS_PM + (size_t)b * NATT * TIN + t;
    for (int a = 0; a < NATT; ++a) {
        float s = pql[a] + pmt[(size_t)a * TIN];
#pragma unroll
        for (int f = 0; f < 32; ++f) s = fmaf(loc[f], ldw[a * 32 + f], s);
        e = fmaf(ftanh(s), vw[a], e);
    }
    if (t >= mlen[b]) e = -3.0e38f;
    float m = e;
#pragma unroll
    for (int sh = 1; sh <= 32; sh <<= 1) m = fmaxf(m, __shfl_xor(m, sh));
    if ((tid & 63) == 0) red[tid >> 6] = m;
    __syncthreads();
    m = fmaxf(fmaxf(fmaxf(red[0], red[1]), fmaxf(red[2], red[3])),
              fmaxf(fmaxf(red[4], red[5]), fmaxf(red[6], red[7])));
    float pv = __expf(e - m);
    float ss = pv;
#pragma unroll
    for (int sh = 1; sh <= 32; sh <<= 1) ss += __shfl_xor(ss, sh);
    if ((tid & 63) == 0) red[8 + (tid >> 6)] = ss;
    __syncthreads();
    float tot = red[8] + red[9] + red[10] + red[11] + red[12] + red[13] + red[14] + red[15];
    float aw = pv / tot;
    ws[WS_AW + b * 512 + t] = aw;
    ws[WS_AWCUM + b * 512 + t] += aw;
    out_align[((size_t)b * TOUT + step) * TIN + t] = aw;
    __syncthreads();
    awl[tid] = aw;
    __syncthreads();
    // ctx: thread = enc dim; 4 independent t-chains
    const float* mb = memory + (size_t)b * TIN * NENC + tid;
    float a0 = 0.f, a1 = 0.f, a2 = 0.f, a3 = 0.f;
    for (int tt = 0; tt < TIN; tt += 4) {
        a0 = fmaf(awl[tt],     mb[(size_t)tt * NENC], a0);
        a1 = fmaf(awl[tt + 1], mb[(size_t)(tt + 1) * NENC], a1);
        a2 = fmaf(awl[tt + 2], mb[(size_t)(tt + 2) * NENC], a2);
        a3 = fmaf(awl[tt + 3], mb[(size_t)(tt + 3) * NENC], a3);
    }
    ws[WS_ACTX + b * NENC + tid] = (a0 + a1) + (a2 + a3);
}

// ---------------- K1: z-main (208 blocks) || fused attention (32 blocks) ----------------
__global__ __launch_bounds__(512) void attn_zmain_kernel(
        const float* __restrict__ dwih, const float* __restrict__ dwhh,
        const float* __restrict__ awih, const float* __restrict__ awhh,
        const float* __restrict__ memory, const int* __restrict__ mlen,
        const float* __restrict__ wc, const float* __restrict__ ldw,
        const float* __restrict__ vw,
        float* __restrict__ ws, float* __restrict__ out_align,
        const float* __restrict__ pre_t1, int step) {
    __shared__ float sm[1168];
    int tid = threadIdx.x, bid = blockIdx.x;
    if (bid < 208) {
        int sidx = bid >> 3;                            // 0..25
        int s = sidx + (sidx < 8 ? 0 : (sidx < 18 ? 4 : 8));
        z_slice_body(dwih, dwhh, awih, awhh, ws, pre_t1,
                     ws + WS_ZD, ws + WS_ZA, s, (bid & 7) * 512 + tid);
    } else {
        attn_body(memory, mlen, wc, ldw, vw, ws, out_align, bid - 208, step, tid, sm);
    }
}

// ---------------- K2: z-actx (64 blocks) ----------------
__global__ __launch_bounds__(512) void zactx_kernel(
        const float* __restrict__ dwih, const float* __restrict__ dwhh,
        const float* __restrict__ awih, const float* __restrict__ awhh,
        float* __restrict__ ws) {
    int sidx = blockIdx.x >> 3;                         // 0..7
    int s = sidx + (sidx < 4 ? 8 : 18);                 // 8-11, 22-25
    z_slice_body(dwih, dwhh, awih, awhh, ws, ws + WS_PRE,
                 ws + WS_ZD, ws + WS_ZA, s, ((int)blockIdx.x & 7) * 512 + (int)threadIdx.x);
}

// ---------------- prologue za (112 blocks: 14 slices x 8) ----------------
__global__ __launch_bounds__(512) void za_prologue_kernel(
        const float* __restrict__ dwih, const float* __restrict__ dwhh,
        const float* __restrict__ awih, const float* __restrict__ awhh,
        float* __restrict__ ws) {
    int s = 20 + ((int)blockIdx.x >> 3);                // 20..33
    z_slice_body(dwih, dwhh, awih, awhh, ws, ws + WS_PRE,
                 ws + WS_ZD, ws + WS_ZA, s, ((int)blockIdx.x & 7) * 512 + (int)threadIdx.x);
}

// ---------------- K3: gates (r9-verified verbatim) ----------------
__global__ __launch_bounds__(512) void gates_kernel(
        const float* __restrict__ abih, const float* __restrict__ abhh,
        const float* __restrict__ qw,
        const float* __restrict__ dbih, const float* __restrict__ dbhh,
        const float* __restrict__ pjw, const float* __restrict__ pjb,
        const float* __restrict__ gtw, const float* __restrict__ gtb,
        float* __restrict__ ws, float* __restrict__ out, int t) {
    __shared__ float sm[NU + NENC];
    int tid = threadIdx.x, bid = blockIdx.x;
    if (bid < 32) {
        if (t < 0) return;
        int b = bid;
        float* DH = ws + WS_DH + (size_t)b * NU;
        float* DC = ws + WS_DC + (size_t)b * NU;
        for (int u = tid; u < NU; u += 512) {
            float zi = dbih[u]          + dbhh[u];
            float zf = dbih[NU + u]     + dbhh[NU + u];
            float zg = dbih[2 * NU + u] + dbhh[2 * NU + u];
            float zo = dbih[3 * NU + u] + dbhh[3 * NU + u];
            for (int s = 0; s < 20; s++) {
                const float* z = ws + WS_ZD + ((size_t)s * NB + b) * NG;
                zi += z[u]; zf += z[NU + u]; zg += z[2 * NU + u]; zo += z[3 * NU + u];
            }
            float c = fsigm(zf) * DC[u] + fsigm(zi) * ftanh(zg);
            float h = fsigm(zo) * ftanh(c);
            DC[u] = c; DH[u] = h; sm[u] = h;
        }
        for (int i = tid; i < NENC; i += 512) sm[NU + i] = ws[WS_ACTX + b * NENC + i];
        __syncthreads();
        int col = tid >> 2, q = tid & 3;
        if (col < 81) {
            const float* wr = (col < 80) ? (pjw + (size_t)col * 1536) : gtw;
            const float* d4 = sm + q * 384;
            const float* w4 = wr + q * 384;
            float s = 0.f;
#pragma unroll
            for (int k4 = 0; k4 < 96; k4++) {
                float4 hv = *(const float4*)(d4 + k4 * 4);
                float4 wv = *(const float4*)(w4 + k4 * 4);
                s = fmaf(hv.x, wv.x, s); s = fmaf(hv.y, wv.y, s);
                s = fmaf(hv.z, wv.z, s); s = fmaf(hv.w, wv.w, s);
            }
            s += __shfl_xor(s, 1); s += __shfl_xor(s, 2);
            if (q == 0) {
                s += (col < 80) ? pjb[col] : gtb[0];
                if (col < 80) out[((size_t)b * NMEL + col) * TOUT + t] = s;
                else          out[(size_t)NB * NMEL * TOUT + (size_t)b * TOUT + t] = s;
            }
        }
    } else {
        int b = bid - 32;
        float* AH = ws + WS_AH + (size_t)b * NU;
        float* AC = ws + WS_AC + (size_t)b * NU;
        for (int u = tid; u < NU; u += 512) {
            float zi = abih[u]          + abhh[u];
            float zf = abih[NU + u]     + abhh[NU + u];
            float zg = abih[2 * NU + u] + abhh[2 * NU + u];
            float zo = abih[3 * NU + u] + abhh[3 * NU + u];
            for (int s = 0; s < 14; s++) {
                const float* z = ws + WS_ZA + ((size_t)s * NB + b) * NG;
                zi += z[u]; zf += z[NU + u]; zg += z[2 * NU + u]; zo += z[3 * NU + u];
            }
            float c = fsigm(zf) * AC[u] + fsigm(zi) * ftanh(zg);
            float h = fsigm(zo) * ftanh(c);
            AC[u] = c; AH[u] = h; sm[u] = h;
        }
        __syncthreads();
        int a = tid >> 2, q = tid & 3;
        if (a < NATT) {
            const float* qr = qw + (size_t)a * NU + q * 256;
            const float* h4 = sm + q * 256;
            float s = 0.f;
#pragma unroll
            for (int k4 = 0; k4 < 64; k4++) {
                float4 hv = *(const float4*)(h4 + k4 * 4);
                float4 wv = *(const float4*)(qr + k4 * 4);
                s = fmaf(hv.x, wv.x, s); s = fmaf(hv.y, wv.y, s);
                s = fmaf(hv.z, wv.z, s); s = fmaf(hv.w, wv.w, s);
            }
            s += __shfl_xor(s, 1); s += __shfl_xor(s, 2);
            if (q == 0) ws[WS_PQ + b * NATT + a] = s;
        }
    }
}

extern "C" void kernel_launch(void* const* d_in, const int* in_sizes, int n_in,
                              void* d_out, int out_size, void* d_ws, size_t ws_size,
                              hipStream_t stream) {
    const float* memory = (const float*)d_in[0];
    const float* dec    = (const float*)d_in[1];
    const int*   mlen   = (const int*)d_in[2];
    const float* pw1    = (const float*)d_in[3];
    const float* pw2    = (const float*)d_in[4];
    const float* awih   = (const float*)d_in[5];
    const float* awhh   = (const float*)d_in[6];
    const float* abih   = (const float*)d_in[7];
    const float* abhh   = (const float*)d_in[8];
    const float* qw     = (const float*)d_in[9];
    const float* mw     = (const float*)d_in[10];
    const float* vw     = (const float*)d_in[11];
    const float* wc     = (const float*)d_in[12];
    const float* ldw    = (const float*)d_in[13];
    const float* dwih   = (const float*)d_in[14];
    const float* dwhh   = (const float*)d_in[15];
    const float* dbih   = (const float*)d_in[16];
    const float* dbhh   = (const float*)d_in[17];
    const float* pjw    = (const float*)d_in[18];
    const float* pjb    = (const float*)d_in[19];
    const float* gtw    = (const float*)d_in[20];
    const float* gtb    = (const float*)d_in[21];
    float* ws  = (float*)d_ws;
    float* out = (float*)d_out;
    float* out_align = out + OUT_ALIGN;

    hipMemsetAsync(ws, 0, WS_STATE_ZERO_BYTES, stream);
    hipMemsetAsync(ws + WS_PRE + (size_t)512 * NB * NPRE, 0, (size_t)NB * NPRE * 4, stream);

    prenet1_kernel<<<TOUT, 256, 0, stream>>>(dec, pw1, ws + WS_PRE);
    prenet2_kernel<<<TOUT, 256, 0, stream>>>(pw2, ws + WS_PRE);
    pmt_kernel<<<dim3(TIN / 4, NB), 128, 0, stream>>>(memory, mw, ws + WS_PM);

    // prologue: za(0) (AH/ACTX zeroed => all 14 za slices), then agates+pq(0)
    za_prologue_kernel<<<112, 512, 0, stream>>>(dwih, dwhh, awih, awhh, ws);
    gates_kernel<<<64, 512, 0, stream>>>(abih, abhh, qw, dbih, dbhh, pjw, pjb,
                                         gtw, gtb, ws, out, -1);

    for (int t = 0; t < TOUT; ++t) {
        attn_zmain_kernel<<<240, 512, 0, stream>>>(
            dwih, dwhh, awih, awhh, memory, mlen, wc, ldw, vw,
            ws, out_align, ws + WS_PRE + (size_t)(t + 1) * NB * NPRE, t);
        zactx_kernel<<<64, 512, 0, stream>>>(dwih, dwhh, awih, awhh, ws);
        gates_kernel<<<64, 512, 0, stream>>>(abih, abhh, qw, dbih, dbhh, pjw, pjb,
                                             gtw, gtb, ws, out, t);
    }
}

// Round 12
// 95714.929 us; speedup vs baseline: 1.1721x; 1.1721x over previous
//
#include <hip/hip_runtime.h>
#include <math.h>

#define NB 32
#define TIN 512
#define TOUT 512
#define NENC 512
#define NATT 128
#define NU 1024
#define NG 4096
#define NPRE 256
#define NMEL 80

// ws offsets (floats)
#define WS_AH    0u
#define WS_AC    32768u
#define WS_DH    65536u
#define WS_DC    98304u
#define WS_ACTX  131072u
#define WS_AW    147456u
#define WS_AWCUM 163840u
#define WS_E     180224u
#define WS_PQ    196608u
#define WS_ZD    200704u                    // 20*32*4096
#define WS_ZA    2822144u                   // 14*32*4096
#define WS_PM    4657152u                   // 32*512*128 [b][t][a]
#define WS_PRE   6754304u                   // 513*32*256 (row 512 = zeros)
#define WS_WBF   10956800u                  // bf16 weights (ushort), 17.8M elems
#define WS_STATE_ZERO_BYTES (200704u * 4u)
#define OUT_ALIGN ((size_t)NB * NMEL * TOUT + (size_t)NB * TOUT)

// bf16 weight sub-offsets (in ushort elements)
#define BW_DIH 0u
#define BW_DHH 6291456u
#define BW_AIH 10485760u
#define BW_AHH 13631488u

__device__ __forceinline__ float fsigm(float x) { return 1.f / (1.f + __expf(-x)); }
__device__ __forceinline__ float ftanh(float x) { return 1.f - 2.f / (__expf(2.f * x) + 1.f); }
__device__ __forceinline__ float bf2f(unsigned short h) { return __uint_as_float((unsigned)h << 16); }

// ---------------- weight pack: fp32 -> bf16 (RNE), once per launch ----------------
__global__ __launch_bounds__(256) void packbf_kernel(const float* __restrict__ src,
                                                     unsigned short* __restrict__ dst, int n) {
    for (int i = blockIdx.x * 256 + threadIdx.x; i < n; i += gridDim.x * 256) {
        unsigned u = __float_as_uint(src[i]);
        dst[i] = (unsigned short)((u + 0x7FFFu + ((u >> 16) & 1u)) >> 16);
    }
}

// ---------------- setup kernels (r9-verified) ----------------
__global__ __launch_bounds__(256) void prenet1_kernel(const float* __restrict__ dec,
                                                      const float* __restrict__ w1,
                                                      float* __restrict__ pre) {
    int t = blockIdx.x;
    __shared__ float xl[NB][NMEL];
    for (int i = threadIdx.x; i < NB * NMEL; i += 256) {
        int b = i / NMEL, m = i % NMEL;
        xl[b][m] = (t == 0) ? 0.0f : dec[(b * NMEL + m) * TOUT + (t - 1)];
    }
    __syncthreads();
    int j = threadIdx.x;
    float acc[NB];
#pragma unroll
    for (int b = 0; b < NB; b++) acc[b] = 0.0f;
    for (int m = 0; m < NMEL; m++) {
        float w = w1[j * NMEL + m];
#pragma unroll
        for (int b = 0; b < NB; b++) acc[b] += xl[b][m] * w;
    }
    for (int b = 0; b < NB; b++) pre[((size_t)t * NB + b) * NPRE + j] = fmaxf(acc[b], 0.0f);
}

__global__ __launch_bounds__(256) void prenet2_kernel(const float* __restrict__ w2,
                                                      float* __restrict__ pre) {
    int t = blockIdx.x;
    __shared__ float hl[NB][NPRE];
    for (int i = threadIdx.x; i < NB * NPRE; i += 256)
        hl[i / NPRE][i % NPRE] = pre[(size_t)t * NB * NPRE + i];
    __syncthreads();
    int j = threadIdx.x;
    float acc[NB];
#pragma unroll
    for (int b = 0; b < NB; b++) acc[b] = 0.0f;
    for (int k = 0; k < NPRE; k++) {
        float w = w2[j * NPRE + k];
#pragma unroll
        for (int b = 0; b < NB; b++) acc[b] += hl[b][k] * w;
    }
    for (int b = 0; b < NB; b++) pre[((size_t)t * NB + b) * NPRE + j] = fmaxf(acc[b], 0.0f);
}

__global__ __launch_bounds__(128) void pm_kernel(const float* __restrict__ mem,
                                                 const float* __restrict__ mw,
                                                 float* __restrict__ pm) {
    int b = blockIdx.y, t0 = blockIdx.x * 4;
    __shared__ float ml[4][NENC];
    for (int i = threadIdx.x; i < 4 * NENC; i += 128)
        ml[i / NENC][i % NENC] = mem[((size_t)b * TIN + t0 + i / NENC) * NENC + (i % NENC)];
    __syncthreads();
    int a = threadIdx.x;
    float acc[4] = {0, 0, 0, 0};
    for (int e = 0; e < NENC; e++) {
        float w = mw[a * NENC + e];
#pragma unroll
        for (int tt = 0; tt < 4; tt++) acc[tt] += ml[tt][e] * w;
    }
    for (int tt = 0; tt < 4; tt++)
        pm[((size_t)b * TIN + t0 + tt) * NATT + a] = acc[tt];
}

// ---------------- fused z GEMV (bf16 weights, r9 lane=column layout) ----------------
// slice s: 0-7 dwih@AH | 8-11 dwih@ACTX | 12-19 dwhh@DH |
//          20-21 awih@PRE(ts) | 22-25 awih@ACTX | 26-33 awhh@AH
__global__ __launch_bounds__(256) void z_fused_kernel(
        const unsigned short* __restrict__ wbf,
        const float* __restrict__ ws_base, const float* __restrict__ pre_t,
        float* __restrict__ zd, float* __restrict__ za, int sbase) {
    int col = blockIdx.x * 256 + threadIdx.x;
    int s = blockIdx.y + sbase;
    const float* ah   = ws_base + WS_AH;
    const float* dh   = ws_base + WS_DH;
    const float* actx = ws_base + WS_ACTX;
    const unsigned short* W; const float* x; int xs;
    if (s < 8)       { W = wbf + BW_DIH + (size_t)col * 1536 + s * 128;              x = ah + s * 128;           xs = NU;   }
    else if (s < 12) { W = wbf + BW_DIH + (size_t)col * 1536 + 1024 + (s - 8) * 128; x = actx + (s - 8) * 128;   xs = NENC; }
    else if (s < 20) { W = wbf + BW_DHH + (size_t)col * 1024 + (s - 12) * 128;       x = dh + (s - 12) * 128;    xs = NU;   }
    else if (s < 22) { W = wbf + BW_AIH + (size_t)col * 768 + (s - 20) * 128;        x = pre_t + (s - 20) * 128; xs = NPRE; }
    else if (s < 26) { W = wbf + BW_AIH + (size_t)col * 768 + 256 + (s - 22) * 128;  x = actx + (s - 22) * 128;  xs = NENC; }
    else             { W = wbf + BW_AHH + (size_t)col * 1024 + (s - 26) * 128;       x = ah + (s - 26) * 128;    xs = NU;   }

    float acc[NB];
#pragma unroll
    for (int b = 0; b < NB; b++) acc[b] = 0.0f;
    for (int k4 = 0; k4 < 32; k4++) {
        ushort4 h4 = *(const ushort4*)(W + k4 * 4);
        float w0 = bf2f(h4.x), w1 = bf2f(h4.y), w2 = bf2f(h4.z), w3 = bf2f(h4.w);
#pragma unroll
        for (int b = 0; b < NB; b++) {
            float4 x4 = *(const float4*)(x + (size_t)b * xs + k4 * 4);  // wave-uniform -> scalar
            acc[b] = fmaf(w0, x4.x, acc[b]);
            acc[b] = fmaf(w1, x4.y, acc[b]);
            acc[b] = fmaf(w2, x4.z, acc[b]);
            acc[b] = fmaf(w3, x4.w, acc[b]);
        }
    }
    float* zp = ((s < 20) ? (zd + (size_t)s * NB * NG) : (za + (size_t)(s - 20) * NB * NG)) + col;
#pragma unroll
    for (int b = 0; b < NB; b++) zp[(size_t)b * NG] = acc[b];
}

// ---------------- r9-verified energies ----------------
__global__ __launch_bounds__(128) void energies_kernel(const float* __restrict__ pm,
                                                       const float* __restrict__ wc,
                                                       const float* __restrict__ ldw,
                                                       const float* __restrict__ vw,
                                                       const int* __restrict__ mlen,
                                                       const float* __restrict__ ws_aw,
                                                       const float* __restrict__ ws_awcum,
                                                       const float* __restrict__ ws_pq,
                                                       float* __restrict__ ws_e) {
    int b = blockIdx.y, tc = blockIdx.x;
    int tt = threadIdx.x & 31, sub = threadIdx.x >> 5;
    int t = tc * 32 + tt;
    __shared__ float awl[TIN], cuml[TIN], locl[32][33], pql[NATT], ep[32][4];
    for (int i = threadIdx.x; i < TIN; i += 128) {
        awl[i]  = ws_aw[b * TIN + i];
        cuml[i] = ws_awcum[b * TIN + i];
    }
    for (int i = threadIdx.x; i < NATT; i += 128) pql[i] = ws_pq[b * NATT + i];
    __syncthreads();
    for (int f = sub * 8; f < sub * 8 + 8; f++) {
        float s = 0.0f;
        const float* wA = wc + f * 62;
        const float* wB = wA + 31;
        for (int d = 0; d < 31; d++) {
            int tp = t + d - 15;
            if (tp >= 0 && tp < TIN) s += awl[tp] * wA[d] + cuml[tp] * wB[d];
        }
        locl[tt][f] = s;
    }
    __syncthreads();
    float acc = 0.0f;
    const float* pmb = pm + ((size_t)b * TIN + t) * NATT;
    for (int a = sub * 32; a < sub * 32 + 32; a++) {
        float s = pql[a] + pmb[a];
        const float* lw = ldw + a * 32;
#pragma unroll
        for (int f = 0; f < 32; f++) s += locl[tt][f] * lw[f];
        acc += tanhf(s) * vw[a];
    }
    ep[tt][sub] = acc;
    __syncthreads();
    if (sub == 0) {
        float ev = ep[tt][0] + ep[tt][1] + ep[tt][2] + ep[tt][3];
        if (t >= mlen[b]) ev = -3.0e38f;
        ws_e[b * TIN + t] = ev;
    }
}

// ---------------- r9-verified softmax + context ----------------
__global__ __launch_bounds__(256) void softmax_ctx_kernel(const float* __restrict__ mem,
                                                          const float* __restrict__ E,
                                                          float* __restrict__ AW,
                                                          float* __restrict__ AWCUM,
                                                          float* __restrict__ ACTX,
                                                          float* __restrict__ out_align, int step) {
    int b = blockIdx.y, ec = blockIdx.x;
    __shared__ float el[TIN];
    __shared__ float red[256];
    __shared__ float part[4][64];
    const float* Eb = E + b * TIN;
    for (int i = threadIdx.x; i < TIN; i += 256) el[i] = Eb[i];
    __syncthreads();
    red[threadIdx.x] = fmaxf(el[threadIdx.x], el[threadIdx.x + 256]);
    __syncthreads();
    for (int s = 128; s > 0; s >>= 1) {
        if (threadIdx.x < s) red[threadIdx.x] = fmaxf(red[threadIdx.x], red[threadIdx.x + s]);
        __syncthreads();
    }
    float mx = red[0];
    __syncthreads();
    float p0 = __expf(el[threadIdx.x] - mx), p1 = __expf(el[threadIdx.x + 256] - mx);
    el[threadIdx.x] = p0; el[threadIdx.x + 256] = p1;
    red[threadIdx.x] = p0 + p1;
    __syncthreads();
    for (int s = 128; s > 0; s >>= 1) {
        if (threadIdx.x < s) red[threadIdx.x] += red[threadIdx.x + s];
        __syncthreads();
    }
    float inv = 1.0f / red[0];
    int ei = ec * 64 + (threadIdx.x & 63), tp4 = threadIdx.x >> 6;
    float acc = 0.0f;
    const float* mb = mem + (size_t)b * TIN * NENC + ei;
    for (int t = tp4 * 128; t < tp4 * 128 + 128; t++) acc += el[t] * mb[(size_t)t * NENC];
    part[tp4][threadIdx.x & 63] = acc;
    __syncthreads();
    if (threadIdx.x < 64) {
        float ctx = (part[0][threadIdx.x] + part[1][threadIdx.x] +
                     part[2][threadIdx.x] + part[3][threadIdx.x]) * inv;
        ACTX[b * NENC + ec * 64 + threadIdx.x] = ctx;
    }
    if (ec == 0) {
        for (int i = threadIdx.x; i < TIN; i += 256) {
            float a_ = el[i] * inv;
            AW[b * TIN + i] = a_;
            AWCUM[b * TIN + i] += a_;
            out_align[((size_t)b * TOUT + step) * TIN + i] = a_;
        }
    }
}

// ---------------- r9-verified gates ----------------
__global__ __launch_bounds__(512) void gates_kernel(
        const float* __restrict__ abih, const float* __restrict__ abhh,
        const float* __restrict__ qw,
        const float* __restrict__ dbih, const float* __restrict__ dbhh,
        const float* __restrict__ pjw, const float* __restrict__ pjb,
        const float* __restrict__ gtw, const float* __restrict__ gtb,
        float* __restrict__ ws, float* __restrict__ out, int t) {
    __shared__ float sm[NU + NENC];
    int tid = threadIdx.x, bid = blockIdx.x;
    if (bid < 32) {
        if (t < 0) return;
        int b = bid;
        float* DH = ws + WS_DH + (size_t)b * NU;
        float* DC = ws + WS_DC + (size_t)b * NU;
        for (int u = tid; u < NU; u += 512) {
            float zi = dbih[u]          + dbhh[u];
            float zf = dbih[NU + u]     + dbhh[NU + u];
            float zg = dbih[2 * NU + u] + dbhh[2 * NU + u];
            float zo = dbih[3 * NU + u] + dbhh[3 * NU + u];
            for (int s = 0; s < 20; s++) {
                const float* z = ws + WS_ZD + ((size_t)s * NB + b) * NG;
                zi += z[u]; zf += z[NU + u]; zg += z[2 * NU + u]; zo += z[3 * NU + u];
            }
            float c = fsigm(zf) * DC[u] + fsigm(zi) * ftanh(zg);
            float h = fsigm(zo) * ftanh(c);
            DC[u] = c; DH[u] = h; sm[u] = h;
        }
        for (int i = tid; i < NENC; i += 512) sm[NU + i] = ws[WS_ACTX + b * NENC + i];
        __syncthreads();
        int col = tid >> 2, q = tid & 3;
        if (col < 81) {
            const float* wr = (col < 80) ? (pjw + (size_t)col * 1536) : gtw;
            const float* d4 = sm + q * 384;
            const float* w4 = wr + q * 384;
            float s = 0.f;
#pragma unroll
            for (int k4 = 0; k4 < 96; k4++) {
                float4 hv = *(const float4*)(d4 + k4 * 4);
                float4 wv = *(const float4*)(w4 + k4 * 4);
                s = fmaf(hv.x, wv.x, s); s = fmaf(hv.y, wv.y, s);
                s = fmaf(hv.z, wv.z, s); s = fmaf(hv.w, wv.w, s);
            }
            s += __shfl_xor(s, 1); s += __shfl_xor(s, 2);
            if (q == 0) {
                s += (col < 80) ? pjb[col] : gtb[0];
                if (col < 80) out[((size_t)b * NMEL + col) * TOUT + t] = s;
                else          out[(size_t)NB * NMEL * TOUT + (size_t)b * TOUT + t] = s;
            }
        }
    } else {
        int b = bid - 32;
        float* AH = ws + WS_AH + (size_t)b * NU;
        float* AC = ws + WS_AC + (size_t)b * NU;
        for (int u = tid; u < NU; u += 512) {
            float zi = abih[u]          + abhh[u];
            float zf = abih[NU + u]     + abhh[NU + u];
            float zg = abih[2 * NU + u] + abhh[2 * NU + u];
            float zo = abih[3 * NU + u] + abhh[3 * NU + u];
            for (int s = 0; s < 14; s++) {
                const float* z = ws + WS_ZA + ((size_t)s * NB + b) * NG;
                zi += z[u]; zf += z[NU + u]; zg += z[2 * NU + u]; zo += z[3 * NU + u];
            }
            float c = fsigm(zf) * AC[u] + fsigm(zi) * ftanh(zg);
            float h = fsigm(zo) * ftanh(c);
            AC[u] = c; AH[u] = h; sm[u] = h;
        }
        __syncthreads();
        int a = tid >> 2, q = tid & 3;
        if (a < NATT) {
            const float* qr = qw + (size_t)a * NU + q * 256;
            const float* h4 = sm + q * 256;
            float s = 0.f;
#pragma unroll
            for (int k4 = 0; k4 < 64; k4++) {
                float4 hv = *(const float4*)(h4 + k4 * 4);
                float4 wv = *(const float4*)(qr + k4 * 4);
                s = fmaf(hv.x, wv.x, s); s = fmaf(hv.y, wv.y, s);
                s = fmaf(hv.z, wv.z, s); s = fmaf(hv.w, wv.w, s);
            }
            s += __shfl_xor(s, 1); s += __shfl_xor(s, 2);
            if (q == 0) ws[WS_PQ + b * NATT + a] = s;
        }
    }
}

extern "C" void kernel_launch(void* const* d_in, const int* in_sizes, int n_in,
                              void* d_out, int out_size, void* d_ws, size_t ws_size,
                              hipStream_t stream) {
    const float* memory = (const float*)d_in[0];
    const float* dec    = (const float*)d_in[1];
    const int*   mlen   = (const int*)d_in[2];
    const float* pw1    = (const float*)d_in[3];
    const float* pw2    = (const float*)d_in[4];
    const float* awih   = (const float*)d_in[5];
    const float* awhh   = (const float*)d_in[6];
    const float* abih   = (const float*)d_in[7];
    const float* abhh   = (const float*)d_in[8];
    const float* qw     = (const float*)d_in[9];
    const float* mw     = (const float*)d_in[10];
    const float* vw     = (const float*)d_in[11];
    const float* wc     = (const float*)d_in[12];
    const float* ldw    = (const float*)d_in[13];
    const float* dwih   = (const float*)d_in[14];
    const float* dwhh   = (const float*)d_in[15];
    const float* dbih   = (const float*)d_in[16];
    const float* dbhh   = (const float*)d_in[17];
    const float* pjw    = (const float*)d_in[18];
    const float* pjb    = (const float*)d_in[19];
    const float* gtw    = (const float*)d_in[20];
    const float* gtb    = (const float*)d_in[21];
    float* ws  = (float*)d_ws;
    float* out = (float*)d_out;
    float* out_align = out + OUT_ALIGN;
    unsigned short* wbf = (unsigned short*)(ws + WS_WBF);

    hipMemsetAsync(ws, 0, WS_STATE_ZERO_BYTES, stream);
    hipMemsetAsync(ws + WS_PRE + (size_t)512 * NB * NPRE, 0, (size_t)NB * NPRE * 4, stream);

    // pack z weights to bf16 (once per launch; deterministic)
    packbf_kernel<<<1024, 256, 0, stream>>>(dwih, wbf + BW_DIH, 4096 * 1536);
    packbf_kernel<<<1024, 256, 0, stream>>>(dwhh, wbf + BW_DHH, 4096 * 1024);
    packbf_kernel<<<1024, 256, 0, stream>>>(awih, wbf + BW_AIH, 4096 * 768);
    packbf_kernel<<<1024, 256, 0, stream>>>(awhh, wbf + BW_AHH, 4096 * 1024);

    prenet1_kernel<<<TOUT, 256, 0, stream>>>(dec, pw1, ws + WS_PRE);
    prenet2_kernel<<<TOUT, 256, 0, stream>>>(pw2, ws + WS_PRE);
    pm_kernel<<<dim3(TIN / 4, NB), 128, 0, stream>>>(memory, mw, ws + WS_PM);

    // prologue: za(0) (AH/ACTX zeroed => all 14 za slices), then agates+pq(0)
    z_fused_kernel<<<dim3(16, 14), 256, 0, stream>>>(
        wbf, ws, ws + WS_PRE, ws + WS_ZD, ws + WS_ZA, 20);
    gates_kernel<<<64, 512, 0, stream>>>(abih, abhh, qw, dbih, dbhh, pjw, pjb,
                                         gtw, gtb, ws, out, -1);

    for (int t = 0; t < TOUT; ++t) {
        energies_kernel<<<dim3(16, NB), 128, 0, stream>>>(
            ws + WS_PM, wc, ldw, vw, mlen,
            ws + WS_AW, ws + WS_AWCUM, ws + WS_PQ, ws + WS_E);
        softmax_ctx_kernel<<<dim3(8, NB), 256, 0, stream>>>(
            memory, ws + WS_E, ws + WS_AW, ws + WS_AWCUM, ws + WS_ACTX, out_align, t);
        z_fused_kernel<<<dim3(16, 34), 256, 0, stream>>>(
            wbf, ws, ws + WS_PRE + (size_t)(t + 1) * NB * NPRE,
            ws + WS_ZD, ws + WS_ZA, 0);
        gates_kernel<<<64, 512, 0, stream>>>(abih, abhh, qw, dbih, dbhh, pjw, pjb,
                                             gtw, gtb, ws, out, t);
    }
}